// Round 3
// baseline (234.042 us; speedup 1.0000x reference)
//
#include <hip/hip_runtime.h>
#include <hip/hip_cooperative_groups.h>
#include <hip/hip_bf16.h>
#include <math.h>

namespace cg = cooperative_groups;

#define NB   256
#define KIN  1024
#define ND   512
#define NP   2048
#define NTOT 4096   // Wm rows + proxy rows stacked

typedef __bf16 bf16x8 __attribute__((ext_vector_type(8)));
typedef float  f32x4  __attribute__((ext_vector_type(4)));
typedef unsigned short ush8 __attribute__((ext_vector_type(8)));

// ws byte offsets (16B aligned)
#define OFF_WPB    0u          // 4096*512 bf16 = 4 MB   (proxy rows pre-scaled by 2)
#define OFF_FEAT32 4194304u    // 256*512 f32   = 512 KB (feat + bias, for row norms)
#define OFF_FEATB  4718592u    // 256*512 bf16  = 256 KB (feat + bias, head A operand)
#define OFF_PN2    4980736u    // 2048 f32      = 8 KB
#define OFF_LOGITS 4988928u    // 256*2048 f32  = 2 MB

__device__ __forceinline__ ush8 pack8(float4 f0, float4 f1) {
    union { ush8 v; __hip_bfloat162 h[4]; } o;
    o.h[0] = __float22bfloat162_rn(make_float2(f0.x, f0.y));
    o.h[1] = __float22bfloat162_rn(make_float2(f0.z, f0.w));
    o.h[2] = __float22bfloat162_rn(make_float2(f1.x, f1.y));
    o.h[3] = __float22bfloat162_rn(make_float2(f1.z, f1.w));
    return o.v;
}
__device__ __forceinline__ unsigned short f2bf(float v) {
    union { __hip_bfloat16 h; unsigned short u; } c;
    c.h = __float2bfloat16(v);
    return c.u;
}
__device__ __forceinline__ bf16x8 ldf8(const float* p) {
    float4 v0 = *(const float4*)p, v1 = *(const float4*)(p + 4);
    union { ush8 u; bf16x8 b; } c;
    c.u = pack8(v0, v1);
    return c.b;
}

__device__ __forceinline__ float block_reduce(float v, float* sred, int op)
{
    const int lane = threadIdx.x & 63, wave = threadIdx.x >> 6;
#pragma unroll
    for (int off = 32; off; off >>= 1) {
        float o = __shfl_down(v, off);
        v = op ? fmaxf(v, o) : (v + o);
    }
    if (lane == 0) sred[wave] = v;
    __syncthreads();
    if (threadIdx.x == 0) {
        float r = sred[0];
#pragma unroll
        for (int wv = 1; wv < 4; ++wv) r = op ? fmaxf(r, sred[wv]) : (r + sred[wv]);
        sred[0] = r;
    }
    __syncthreads();
    float r = sred[0];
    __syncthreads();
    return r;
}

// ---------------------------------------------------------------------------
// Single cooperative kernel, 256 blocks x 256 threads.
//  Stage A: blocks 0..127  : feat 32x32 tile, split-K=4 over the 4 waves
//                            (8 reg-direct K-steps each), LDS 4-way reduce,
//                            write feat32 (f32+bias) + featb (bf16).
//           blocks 128..255: cast Wm(x1)/prox(x2) -> WPb, pn2, zero tail.
//  grid.sync
//  Stage B: all 256 blocks : head GEMM 64x64 tile, LDS dbuf (round-0 proven),
//                            out = v + bm | logits = v - pn2.
//  grid.sync
//  Stage C: block b = row b : logsumexp + gather + row norm -> atomic tail.
// ---------------------------------------------------------------------------
__global__ __launch_bounds__(256) void k_all(
    const float* __restrict__ x, const int* __restrict__ y,
    const float* __restrict__ Wb, const float* __restrict__ bb,
    const float* __restrict__ Wm, const float* __restrict__ bm,
    const float* __restrict__ prox,
    unsigned short* __restrict__ WPb, float* __restrict__ pn2,
    float* __restrict__ feat32, unsigned short* __restrict__ featb,
    float* __restrict__ logits, float* __restrict__ out,
    float* __restrict__ tail)
{
    cg::grid_group grid = cg::this_grid();
    const int t = threadIdx.x, lane = t & 63, w = t >> 6;
    // 4 waves x 32x32 f32 tile, row stride 33 (pad) = 16.9 KB; reused by B/C.
    __shared__ __align__(16) float smemf[4 * 1056];

    // ============================ Stage A ============================
    if (blockIdx.x >= 128) {
        const int pb = blockIdx.x - 128;           // 0..127, 32 rows each
        if (pb == 0 && t < 2) tail[t] = 0.f;
#pragma unroll
        for (int i = 0; i < 8; ++i) {
            const int r = pb * 32 + w * 8 + i;     // 0..4095
            const float* src = (r < NP) ? (Wm + (size_t)r * ND)
                                        : (prox + (size_t)(r - NP) * ND);
            float4 v0 = *(const float4*)(src + lane * 8);
            float4 v1 = *(const float4*)(src + lane * 8 + 4);
            if (r < NP) {
                *(ush8*)(WPb + (size_t)r * ND + lane * 8) = pack8(v0, v1);
            } else {
                float s = v0.x*v0.x + v0.y*v0.y + v0.z*v0.z + v0.w*v0.w
                        + v1.x*v1.x + v1.y*v1.y + v1.z*v1.z + v1.w*v1.w;
#pragma unroll
                for (int off = 32; off; off >>= 1) s += __shfl_down(s, off);
                if (lane == 0) pn2[r - NP] = s;
                // 2*prox: bf16(2v) == 2*bf16(v) exactly (exponent shift)
                float4 d0 = make_float4(v0.x + v0.x, v0.y + v0.y,
                                        v0.z + v0.z, v0.w + v0.w);
                float4 d1 = make_float4(v1.x + v1.x, v1.y + v1.y,
                                        v1.z + v1.z, v1.w + v1.w);
                *(ush8*)(WPb + (size_t)r * ND + lane * 8) = pack8(d0, d1);
            }
        }
    } else {
        // feat: 8 m-tiles x 16 n-tiles of 32x32; wave w covers K quarter
        const int m0 = (blockIdx.x >> 4) * 32, n0 = (blockIdx.x & 15) * 32;
        const int fr = lane & 15, ck = (lane >> 4) * 8;
        const float* pA0 = x  + (size_t)(m0 + fr) * KIN + w * 256 + ck;
        const float* pA1 = pA0 + 16 * KIN;
        const float* pB0 = Wb + (size_t)(n0 + fr) * KIN + w * 256 + ck;
        const float* pB1 = pB0 + 16 * KIN;
        f32x4 acc[2][2] = {};
#pragma unroll
        for (int ks = 0; ks < 8; ++ks) {
            const int off = ks * 32;
            bf16x8 af0 = ldf8(pA0 + off);
            bf16x8 af1 = ldf8(pA1 + off);
            bf16x8 bf0 = ldf8(pB0 + off);
            bf16x8 bf1 = ldf8(pB1 + off);
            acc[0][0] = __builtin_amdgcn_mfma_f32_16x16x32_bf16(af0, bf0, acc[0][0], 0, 0, 0);
            acc[0][1] = __builtin_amdgcn_mfma_f32_16x16x32_bf16(af0, bf1, acc[0][1], 0, 0, 0);
            acc[1][0] = __builtin_amdgcn_mfma_f32_16x16x32_bf16(af1, bf0, acc[1][0], 0, 0, 0);
            acc[1][1] = __builtin_amdgcn_mfma_f32_16x16x32_bf16(af1, bf1, acc[1][1], 0, 0, 0);
        }
        // 4-way split-K reduce through LDS
        float* red = smemf + w * 1056;
        const int q = lane >> 4;
#pragma unroll
        for (int i = 0; i < 2; ++i)
#pragma unroll
            for (int j = 0; j < 2; ++j)
#pragma unroll
                for (int r = 0; r < 4; ++r)
                    red[(16 * i + q * 4 + r) * 33 + 16 * j + fr] = acc[i][j][r];
        __syncthreads();
#pragma unroll
        for (int e = t; e < 1024; e += 256) {
            const int row = e >> 5, col = e & 31;
            const int idx = row * 33 + col;
            float v = smemf[idx] + smemf[idx + 1056]
                    + smemf[idx + 2112] + smemf[idx + 3168];
            const int n = n0 + col;
            const float val = v + bb[n];
            feat32[(m0 + row) * ND + n] = val;
            featb [(m0 + row) * ND + n] = f2bf(val);
        }
    }

    __threadfence();
    grid.sync();

    // ============================ Stage B ============================
    {
        unsigned short* As = (unsigned short*)smemf;   // [2][64*32]
        unsigned short* Bs = As + 4096;                // [2][64*32]
        const int n0 = (blockIdx.x & 63) * 64;         // 64 n-tiles over 4096
        const int m0 = (blockIdx.x >> 6) * 64;         // 4 m-tiles over 256
        const int srow = t >> 2, sc = (t & 3) * 8;
        const unsigned short* gA = featb + (size_t)(m0 + srow) * ND + sc;
        const unsigned short* gB = WPb   + (size_t)(n0 + srow) * ND + sc;
        ush8 va = *(const ush8*)gA;
        ush8 vb = *(const ush8*)gB;
        f32x4 acc[2][2] = {};
        const int wm = (w >> 1) * 32, wn = (w & 1) * 32;
        const int fr = lane & 15, fcol = (lane >> 4) * 8;

        for (int ks = 0; ks < ND / 32; ++ks) {
            *(ush8*)&As[(ks & 1) * 2048 + srow * 32 + sc] = va;
            *(ush8*)&Bs[(ks & 1) * 2048 + srow * 32 + sc] = vb;
            __syncthreads();
            if (ks + 1 < ND / 32) {
                va = *(const ush8*)(gA + (ks + 1) * 32);
                vb = *(const ush8*)(gB + (ks + 1) * 32);
            }
            const unsigned short* as = &As[(ks & 1) * 2048];
            const unsigned short* bs = &Bs[(ks & 1) * 2048];
            bf16x8 af0 = *(const bf16x8*)&as[(wm      + fr) * 32 + fcol];
            bf16x8 af1 = *(const bf16x8*)&as[(wm + 16 + fr) * 32 + fcol];
            bf16x8 bf0 = *(const bf16x8*)&bs[(wn      + fr) * 32 + fcol];
            bf16x8 bf1 = *(const bf16x8*)&bs[(wn + 16 + fr) * 32 + fcol];
            acc[0][0] = __builtin_amdgcn_mfma_f32_16x16x32_bf16(af0, bf0, acc[0][0], 0, 0, 0);
            acc[0][1] = __builtin_amdgcn_mfma_f32_16x16x32_bf16(af0, bf1, acc[0][1], 0, 0, 0);
            acc[1][0] = __builtin_amdgcn_mfma_f32_16x16x32_bf16(af1, bf0, acc[1][0], 0, 0, 0);
            acc[1][1] = __builtin_amdgcn_mfma_f32_16x16x32_bf16(af1, bf1, acc[1][1], 0, 0, 0);
        }

        const bool isProxy = (n0 >= NP);
        const int q = lane >> 4;
#pragma unroll
        for (int i = 0; i < 2; ++i)
#pragma unroll
            for (int j = 0; j < 2; ++j) {
                const int n = n0 + wn + 16 * j + fr;
                const float cadd = isProxy ? pn2[n - NP] : bm[n];
#pragma unroll
                for (int r = 0; r < 4; ++r) {
                    const int m = m0 + wm + 16 * i + q * 4 + r;
                    const float v = acc[i][j][r];
                    if (isProxy) logits[m * NP + (n - NP)] = v - cadd;
                    else         out[m * NP + n] = v + cadd;
                }
            }
    }

    __threadfence();
    grid.sync();

    // ============================ Stage C ============================
    {
        float* sred = smemf;
        const int b = blockIdx.x;

        float v0 = feat32[b * ND + t];          // bias already folded in
        float v1 = feat32[b * ND + t + 256];
        float fn2 = block_reduce(v0 * v0 + v1 * v1, sred, 0);

        const float* lr = logits + (size_t)b * NP;
        float lv[8], mx = -INFINITY;
#pragma unroll
        for (int j = 0; j < 8; ++j) { lv[j] = lr[t + 256 * j]; mx = fmaxf(mx, lv[j]); }
        float MX = block_reduce(mx, sred, 1);
        float es = 0.f;
#pragma unroll
        for (int j = 0; j < 8; ++j) es += __expf(lv[j] - MX);
        float SUM = block_reduce(es, sred, 0);

        if (t == 0) {
            float ly = lr[y[b]];
            float lp = ly - MX - __logf(SUM);
            atomicAdd(&tail[0], -lp * (1.0f / (float)NB));
            atomicAdd(&tail[1], sqrtf(fn2) * (1.0f / (float)NB));
        }
    }
}

extern "C" void kernel_launch(void* const* d_in, const int* in_sizes, int n_in,
                              void* d_out, int out_size, void* d_ws, size_t ws_size,
                              hipStream_t stream)
{
    const float* x       = (const float*)d_in[0];
    const int*   y       = (const int*)  d_in[1];
    const float* Wb      = (const float*)d_in[2];
    const float* bb      = (const float*)d_in[3];
    const float* Wm      = (const float*)d_in[4];
    const float* bm      = (const float*)d_in[5];
    const float* proxies = (const float*)d_in[6];

    char* ws = (char*)d_ws;
    unsigned short* WPb    = (unsigned short*)(ws + OFF_WPB);
    float*          feat32 = (float*)(ws + OFF_FEAT32);
    unsigned short* featb  = (unsigned short*)(ws + OFF_FEATB);
    float*          pn2    = (float*)(ws + OFF_PN2);
    float*          logits = (float*)(ws + OFF_LOGITS);

    float* out  = (float*)d_out;
    float* tail = out + (size_t)NB * NP;

    void* args[] = { (void*)&x, (void*)&y, (void*)&Wb, (void*)&bb,
                     (void*)&Wm, (void*)&bm, (void*)&proxies,
                     (void*)&WPb, (void*)&pn2, (void*)&feat32, (void*)&featb,
                     (void*)&logits, (void*)&out, (void*)&tail };
    hipLaunchCooperativeKernel((void*)k_all, dim3(256), dim3(256),
                               args, 0, stream);
}

// Round 4
// 99.719 us; speedup vs baseline: 2.3470x; 2.3470x over previous
//
#include <hip/hip_runtime.h>
#include <hip/hip_bf16.h>
#include <math.h>

#define NB   256
#define KIN  1024
#define ND   512
#define NP   2048
#define NTOT 4096   // Wm rows + proxy rows stacked

typedef __bf16 bf16x8 __attribute__((ext_vector_type(8)));
typedef float  f32x4  __attribute__((ext_vector_type(4)));
typedef unsigned short ush8 __attribute__((ext_vector_type(8)));

// ws byte offsets (16B aligned)
#define OFF_WPB    0u          // 4096*512 bf16 = 4 MB   (proxy rows pre-scaled by 2)
#define OFF_FEAT32 4194304u    // 256*512 f32   = 512 KB (feat + bias, for row norms)
#define OFF_FEATB  4718592u    // 256*512 bf16  = 256 KB (feat + bias, head A operand)
#define OFF_PN2    4980736u    // 2048 f32      = 8 KB
#define OFF_LOGITS 4988928u    // 256*2048 f32  = 2 MB

__device__ __forceinline__ ush8 pack8(float4 f0, float4 f1) {
    union { ush8 v; __hip_bfloat162 h[4]; } o;
    o.h[0] = __float22bfloat162_rn(make_float2(f0.x, f0.y));
    o.h[1] = __float22bfloat162_rn(make_float2(f0.z, f0.w));
    o.h[2] = __float22bfloat162_rn(make_float2(f1.x, f1.y));
    o.h[3] = __float22bfloat162_rn(make_float2(f1.z, f1.w));
    return o.v;
}
__device__ __forceinline__ unsigned short f2bf(float v) {
    union { __hip_bfloat16 h; unsigned short u; } c;
    c.h = __float2bfloat16(v);
    return c.u;
}
// load 8 consecutive fp32, convert to bf16x8 fragment (register-only)
__device__ __forceinline__ bf16x8 ldf8(const float* p) {
    float4 v0 = *(const float4*)p, v1 = *(const float4*)(p + 4);
    union { ush8 u; bf16x8 b; } c;
    c.u = pack8(v0, v1);
    return c.b;
}

// ---------------------------------------------------------------------------
// K1: fused prep + feat. 384 blocks.
//  blocks 0..127  : feat GEMM, one 32x32 tile per block (8 m x 16 n tiles),
//                   split-K=4 across the block's 4 waves (K=256 each, 8
//                   reg-direct steps -> fully pipelinable, ONE barrier),
//                   4-way LDS reduce, write feat32 (f32+bias) + featb (bf16).
//  blocks 128..383: cast Wm (x1) / prox (x2) -> WPb, pn2 = ||prox||^2,
//                   block 128 zeroes the tail accumulators.
// No global atomics anywhere; k2 depends on featb+WPb only.
// ---------------------------------------------------------------------------
__global__ __launch_bounds__(256) void k1_featprep(
    const float* __restrict__ x, const float* __restrict__ Wb,
    const float* __restrict__ bb,
    const float* __restrict__ Wm, const float* __restrict__ prox,
    unsigned short* __restrict__ WPb, float* __restrict__ pn2,
    float* __restrict__ feat32, unsigned short* __restrict__ featb,
    float* __restrict__ tail)
{
    __shared__ __align__(16) float smemf[4 * 1056];   // 4 waves x 32x33 f32
    const int t = threadIdx.x, lane = t & 63, w = t >> 6;

    if (blockIdx.x >= 128) {
        // ---------------- prep: cast 16 rows per block ----------------
        const int pb = blockIdx.x - 128;           // 0..255
        if (pb == 0 && t < 2) tail[t] = 0.f;       // zero loss accumulators
#pragma unroll
        for (int i = 0; i < 4; ++i) {
            const int r = pb * 16 + w * 4 + i;     // 0..4095
            const float* src = (r < NP) ? (Wm + (size_t)r * ND)
                                        : (prox + (size_t)(r - NP) * ND);
            float4 v0 = *(const float4*)(src + lane * 8);
            float4 v1 = *(const float4*)(src + lane * 8 + 4);
            if (r < NP) {
                *(ush8*)(WPb + (size_t)r * ND + lane * 8) = pack8(v0, v1);
            } else {
                float s = v0.x*v0.x + v0.y*v0.y + v0.z*v0.z + v0.w*v0.w
                        + v1.x*v1.x + v1.y*v1.y + v1.z*v1.z + v1.w*v1.w;
#pragma unroll
                for (int off = 32; off; off >>= 1) s += __shfl_down(s, off);
                if (lane == 0) pn2[r - NP] = s;
                // store 2*prox so head epilogue is uniformly v +/- cadd.
                // bf16(2v) == 2*bf16(v) exactly (exponent shift).
                float4 d0 = make_float4(v0.x + v0.x, v0.y + v0.y,
                                        v0.z + v0.z, v0.w + v0.w);
                float4 d1 = make_float4(v1.x + v1.x, v1.y + v1.y,
                                        v1.z + v1.z, v1.w + v1.w);
                *(ush8*)(WPb + (size_t)r * ND + lane * 8) = pack8(d0, d1);
            }
        }
        return;
    }

    // -------- feat: one 32x32 tile, wave w owns K in [w*256, w*256+256) ------
    const int m0 = (blockIdx.x >> 4) * 32, n0 = (blockIdx.x & 15) * 32;
    const int fr = lane & 15, ck = (lane >> 4) * 8;
    const float* pA0 = x  + (size_t)(m0 + fr) * KIN + w * 256 + ck;
    const float* pA1 = pA0 + 16 * KIN;
    const float* pB0 = Wb + (size_t)(n0 + fr) * KIN + w * 256 + ck;
    const float* pB1 = pB0 + 16 * KIN;
    f32x4 acc[2][2] = {};
#pragma unroll
    for (int ks = 0; ks < 8; ++ks) {
        const int off = ks * 32;
        bf16x8 af0 = ldf8(pA0 + off);
        bf16x8 af1 = ldf8(pA1 + off);
        bf16x8 bf0 = ldf8(pB0 + off);
        bf16x8 bf1 = ldf8(pB1 + off);
        acc[0][0] = __builtin_amdgcn_mfma_f32_16x16x32_bf16(af0, bf0, acc[0][0], 0, 0, 0);
        acc[0][1] = __builtin_amdgcn_mfma_f32_16x16x32_bf16(af0, bf1, acc[0][1], 0, 0, 0);
        acc[1][0] = __builtin_amdgcn_mfma_f32_16x16x32_bf16(af1, bf0, acc[1][0], 0, 0, 0);
        acc[1][1] = __builtin_amdgcn_mfma_f32_16x16x32_bf16(af1, bf1, acc[1][1], 0, 0, 0);
    }
    // 4-way split-K reduce through LDS
    float* red = smemf + w * 1056;
    const int q = lane >> 4;
#pragma unroll
    for (int i = 0; i < 2; ++i)
#pragma unroll
        for (int j = 0; j < 2; ++j)
#pragma unroll
            for (int r = 0; r < 4; ++r)
                red[(16 * i + q * 4 + r) * 33 + 16 * j + fr] = acc[i][j][r];
    __syncthreads();
#pragma unroll
    for (int e = t; e < 1024; e += 256) {
        const int row = e >> 5, col = e & 31;
        const int idx = row * 33 + col;
        float v = smemf[idx] + smemf[idx + 1056]
                + smemf[idx + 2112] + smemf[idx + 3168];
        const int n = n0 + col;
        const float val = v + bb[n];
        feat32[(m0 + row) * ND + n] = val;
        featb [(m0 + row) * ND + n] = f2bf(val);
    }
}

// ---------------------------------------------------------------------------
// K2: head GEMM, 64x64 tile x 256 blocks, LDS dbuf (round-0 proven structure).
// A and B both bf16 -> pure 16B copies into LDS (no in-loop cvt/bias).
// n<2048: out = v + bm ; n>=2048: logits = v - pn2 (WPb proxy rows hold 2x).
// ---------------------------------------------------------------------------
__global__ __launch_bounds__(256) void k2_head(
    const unsigned short* __restrict__ featb,
    const unsigned short* __restrict__ WPb,
    const float* __restrict__ bm, const float* __restrict__ pn2,
    float* __restrict__ out, float* __restrict__ logits)
{
    __shared__ unsigned short As[2][64 * 32];
    __shared__ unsigned short Bs[2][64 * 32];
    const int t = threadIdx.x, lane = t & 63, w = t >> 6;
    const int n0 = blockIdx.x * 64;   // 64 n-tiles over 4096
    const int m0 = blockIdx.y * 64;   // 4 m-tiles over 256
    const int srow = t >> 2, sc = (t & 3) * 8;
    const unsigned short* gA = featb + (size_t)(m0 + srow) * ND + sc;
    const unsigned short* gB = WPb   + (size_t)(n0 + srow) * ND + sc;
    ush8 va = *(const ush8*)gA;
    ush8 vb = *(const ush8*)gB;
    f32x4 acc[2][2] = {};
    const int wm = (w >> 1) * 32, wn = (w & 1) * 32;
    const int fr = lane & 15, fcol = (lane >> 4) * 8;

    for (int ks = 0; ks < ND / 32; ++ks) {
        *(ush8*)&As[ks & 1][srow * 32 + sc] = va;
        *(ush8*)&Bs[ks & 1][srow * 32 + sc] = vb;
        __syncthreads();
        if (ks + 1 < ND / 32) {
            va = *(const ush8*)(gA + (ks + 1) * 32);
            vb = *(const ush8*)(gB + (ks + 1) * 32);
        }
        const unsigned short* as = &As[ks & 1][0];
        const unsigned short* bs = &Bs[ks & 1][0];
        bf16x8 af0 = *(const bf16x8*)&as[(wm      + fr) * 32 + fcol];
        bf16x8 af1 = *(const bf16x8*)&as[(wm + 16 + fr) * 32 + fcol];
        bf16x8 bf0 = *(const bf16x8*)&bs[(wn      + fr) * 32 + fcol];
        bf16x8 bf1 = *(const bf16x8*)&bs[(wn + 16 + fr) * 32 + fcol];
        acc[0][0] = __builtin_amdgcn_mfma_f32_16x16x32_bf16(af0, bf0, acc[0][0], 0, 0, 0);
        acc[0][1] = __builtin_amdgcn_mfma_f32_16x16x32_bf16(af0, bf1, acc[0][1], 0, 0, 0);
        acc[1][0] = __builtin_amdgcn_mfma_f32_16x16x32_bf16(af1, bf0, acc[1][0], 0, 0, 0);
        acc[1][1] = __builtin_amdgcn_mfma_f32_16x16x32_bf16(af1, bf1, acc[1][1], 0, 0, 0);
    }

    const bool isProxy = (n0 >= NP);
    const int q = lane >> 4;
#pragma unroll
    for (int i = 0; i < 2; ++i)
#pragma unroll
        for (int j = 0; j < 2; ++j) {
            const int n = n0 + wn + 16 * j + fr;
            const float cadd = isProxy ? pn2[n - NP] : bm[n];
#pragma unroll
            for (int r = 0; r < 4; ++r) {
                const int m = m0 + wm + 16 * i + q * 4 + r;
                const float v = acc[i][j][r];
                if (isProxy) logits[m * NP + (n - NP)] = v - cadd;
                else         out[m * NP + n] = v + cadd;
            }
        }
}

__device__ __forceinline__ float block_reduce(float v, float* sred, int op)
{
    const int lane = threadIdx.x & 63, wave = threadIdx.x >> 6;
#pragma unroll
    for (int off = 32; off; off >>= 1) {
        float o = __shfl_down(v, off);
        v = op ? fmaxf(v, o) : (v + o);
    }
    if (lane == 0) sred[wave] = v;
    __syncthreads();
    if (threadIdx.x == 0) {
        float r = sred[0];
#pragma unroll
        for (int wv = 1; wv < 4; ++wv) r = op ? fmaxf(r, sred[wv]) : (r + sred[wv]);
        sred[0] = r;
    }
    __syncthreads();
    float r = sred[0];
    __syncthreads();
    return r;
}

// K3: per-row logsumexp + gather + feat row norm, accumulated straight into
// the two output tail scalars.
__global__ __launch_bounds__(256) void k3_loss(
    const float* __restrict__ feat32, const float* __restrict__ logits,
    const int* __restrict__ y, float* __restrict__ tail)
{
    __shared__ float sred[4];
    const int b = blockIdx.x, t = threadIdx.x;

    float v0 = feat32[b * ND + t];           // bias already folded in
    float v1 = feat32[b * ND + t + 256];
    float fn2 = block_reduce(v0 * v0 + v1 * v1, sred, 0);

    const float* lr = logits + (size_t)b * NP;
    float lv[8], mx = -INFINITY;
#pragma unroll
    for (int j = 0; j < 8; ++j) { lv[j] = lr[t + 256 * j]; mx = fmaxf(mx, lv[j]); }
    float MX = block_reduce(mx, sred, 1);
    float es = 0.f;
#pragma unroll
    for (int j = 0; j < 8; ++j) es += __expf(lv[j] - MX);
    float SUM = block_reduce(es, sred, 0);

    if (t == 0) {
        float ly = lr[y[b]];
        float lp = ly - MX - __logf(SUM);
        atomicAdd(&tail[0], -lp * (1.0f / (float)NB));
        atomicAdd(&tail[1], sqrtf(fn2) * (1.0f / (float)NB));
    }
}

extern "C" void kernel_launch(void* const* d_in, const int* in_sizes, int n_in,
                              void* d_out, int out_size, void* d_ws, size_t ws_size,
                              hipStream_t stream)
{
    const float* x       = (const float*)d_in[0];
    const int*   y       = (const int*)  d_in[1];
    const float* Wb      = (const float*)d_in[2];
    const float* bb      = (const float*)d_in[3];
    const float* Wm      = (const float*)d_in[4];
    const float* bm      = (const float*)d_in[5];
    const float* proxies = (const float*)d_in[6];

    char* ws = (char*)d_ws;
    unsigned short* WPb    = (unsigned short*)(ws + OFF_WPB);
    float*          feat32 = (float*)(ws + OFF_FEAT32);
    unsigned short* featb  = (unsigned short*)(ws + OFF_FEATB);
    float*          pn2    = (float*)(ws + OFF_PN2);
    float*          logits = (float*)(ws + OFF_LOGITS);

    float* out  = (float*)d_out;
    float* tail = out + (size_t)NB * NP;

    k1_featprep<<<dim3(384), dim3(256), 0, stream>>>(
        x, Wb, bb, Wm, proxies, WPb, pn2, feat32, featb, tail);
    k2_head<<<dim3(NTOT / 64, NB / 64), dim3(256), 0, stream>>>(
        featb, WPb, bm, pn2, out, logits);
    k3_loss<<<dim3(NB), dim3(256), 0, stream>>>(feat32, logits, y, tail);
}